// Round 2
// baseline (46.342 us; speedup 1.0000x reference)
//
#include <hip/hip_runtime.h>
#include <math.h>

// Problem constants (match reference setup_inputs)
#define B 32
#define S 4096
#define E 256
#define H 256
#define T 64
#define J (T - 2)

// Kernel A: per segment g=(b,tau): t[g] = dot(column-mean of enc rows in seg, We).
// One block (256 threads = 4 waves) per segment. Lane i owns features 4i..4i+3
// (float4). Wave w accumulates rows st+w, st+w+4, ... (stride 4), then the 4
// wave partials are combined through LDS and dotted with We once per segment.
// Hot loop: one coalesced 16B load + 4 adds per lane per row -> pure HBM stream.
__global__ __launch_bounds__(256) void seg_dot_kernel(
    const float* __restrict__ enc,
    const int* __restrict__ ends,
    const float* __restrict__ We,
    float* __restrict__ t) {
    const int g    = blockIdx.x;        // segment id = b*T + tau
    const int tau  = g & (T - 1);
    const int b    = g >> 6;            // T == 64
    const int w    = threadIdx.x >> 6;
    const int lane = threadIdx.x & 63;

    const int e  = ends[g];
    const int st = (tau == 0) ? 0 : (ends[g - 1] + 1);

    const float4* base = reinterpret_cast<const float4*>(enc + (size_t)b * S * E);
    float4 acc = {0.f, 0.f, 0.f, 0.f};
#pragma unroll 4
    for (int r = st + w; r <= e; r += 4) {
        float4 v = base[(size_t)r * 64 + lane];
        acc.x += v.x; acc.y += v.y; acc.z += v.z; acc.w += v.w;
    }

    __shared__ float4 lds[256];
    lds[threadIdx.x] = acc;
    __syncthreads();

    if (w == 0) {
        float4 a0 = lds[lane];
        float4 a1 = lds[64 + lane];
        float4 a2 = lds[128 + lane];
        float4 a3 = lds[192 + lane];
        float4 wv = reinterpret_cast<const float4*>(We)[lane];
        float p = (a0.x + a1.x + a2.x + a3.x) * wv.x
                + (a0.y + a1.y + a2.y + a3.y) * wv.y
                + (a0.z + a1.z + a2.z + a3.z) * wv.z
                + (a0.w + a1.w + a2.w + a3.w) * wv.w;
#pragma unroll
        for (int off = 32; off >= 1; off >>= 1)
            p += __shfl_xor(p, off, 64);
        if (lane == 0) t[g] = p / (float)(e - st + 1);
    }
}

// Kernel B: single block. Load all B*T t-values into LDS, compute
// loss[b,j] = LSE_{m=j+2..T-1}(t[b,m]) - t[b,j+2], reduce to the mean.
__global__ __launch_bounds__(512) void loss_kernel(
    const float* __restrict__ t,
    float* __restrict__ out) {
    __shared__ float tt[B * T];
    __shared__ float partial[8];
    const int tid = threadIdx.x;

    for (int i = tid; i < B * T; i += 512) tt[i] = t[i];
    __syncthreads();

    float sum = 0.f;
    for (int item = tid; item < B * J; item += 512) {
        const int b = item / J;
        const int j = item - b * J;
        const float* tb = tt + b * T;
        float M = -1e30f;
        for (int m = j + 2; m < T; ++m) M = fmaxf(M, tb[m]);
        float acc = 0.f;
        for (int m = j + 2; m < T; ++m) acc += __expf(tb[m] - M);
        sum += logf(acc) + M - tb[j + 2];
    }

#pragma unroll
    for (int off = 32; off >= 1; off >>= 1)
        sum += __shfl_xor(sum, off, 64);
    if ((tid & 63) == 0) partial[tid >> 6] = sum;
    __syncthreads();

    if (tid == 0) {
        float tot = 0.f;
        for (int i = 0; i < 8; ++i) tot += partial[i];
        out[0] = tot / (float)(B * J);
    }
}

extern "C" void kernel_launch(void* const* d_in, const int* in_sizes, int n_in,
                              void* d_out, int out_size, void* d_ws, size_t ws_size,
                              hipStream_t stream) {
    // Inputs: 0 encoder_output (B,S,E) f32; 1 his_turn_end_ids (B,T) i32;
    // 2..5 LSTM weights (algebraically dead); 6 fc_w (1,H+E); 7 fc_b (dead).
    // loss[b,j] = LSE_{m=j+2..T-1}(t[b,m]) - t[b,j+2], t = seg_mean(enc) @ We,
    // We = fc_w[0, H:]. The LSTM path and fc_b cancel inside LSE - logits[...,0].
    const float* enc  = (const float*)d_in[0];
    const int*   ends = (const int*)d_in[1];
    const float* We   = (const float*)d_in[6] + H;

    float* t   = (float*)d_ws;   // B*T floats = 8 KiB
    float* out = (float*)d_out;

    seg_dot_kernel<<<B * T, 256, 0, stream>>>(enc, ends, We, t);
    loss_kernel<<<1, 512, 0, stream>>>(t, out);
}

// Round 3
// 38.485 us; speedup vs baseline: 1.2042x; 1.2042x over previous
//
#include <hip/hip_runtime.h>
#include <math.h>

// Problem constants (match reference setup_inputs)
#define B 32
#define S 4096
#define E 256
#define H 256
#define T 64
#define J (T - 2)

// Kernel 1 (R1-proven streamer): d[b*S+s] = dot(encoder_output[b,s,:], We)
// One 64-lane wave per row; lane i handles float4 at element 4*i (E=256=64*4).
__global__ __launch_bounds__(256) void row_dot_kernel(
    const float* __restrict__ enc,
    const float* __restrict__ We,
    float* __restrict__ d) {
    const int gid  = blockIdx.x * blockDim.x + threadIdx.x;
    const int row  = gid >> 6;          // wave index == row index
    const int lane = threadIdx.x & 63;

    const float4* rowp = reinterpret_cast<const float4*>(enc + (size_t)row * E);
    const float4  v = rowp[lane];
    const float4  w = reinterpret_cast<const float4*>(We)[lane];
    float p = v.x * w.x + v.y * w.y + v.z * w.z + v.w * w.w;

#pragma unroll
    for (int off = 32; off >= 1; off >>= 1)
        p += __shfl_xor(p, off, 64);

    if (lane == 0) d[row] = p;
}

// Kernel 2: one block per batch. Stage d[b,:] in LDS (padded), segment means,
// loss[b,j] = LSE_{m=j+2..T-1}(tt[m]) - tt[j+2], block-reduce -> loss_b[b].
#define PAD(i) ((i) + ((i) >> 5))
__global__ __launch_bounds__(256) void batch_loss_kernel(
    const float* __restrict__ d,
    const int* __restrict__ ends,
    float* __restrict__ loss_b) {
    const int b   = blockIdx.x;
    const int tid = threadIdx.x;

    __shared__ float ds[S + (S >> 5)];  // padded to break stride-64 bank conflicts
    __shared__ float tt[T];
    __shared__ float partial[4];

    // Stage 16 KB of d: 4 float4 per thread, coalesced.
    const float4* dp = reinterpret_cast<const float4*>(d + (size_t)b * S);
#pragma unroll
    for (int k = 0; k < 4; ++k) {
        float4 v = dp[tid + k * 256];
        int i = 4 * (tid + k * 256);
        ds[PAD(i)]     = v.x;
        ds[PAD(i + 1)] = v.y;
        ds[PAD(i + 2)] = v.z;
        ds[PAD(i + 3)] = v.w;
    }
    __syncthreads();

    // Segment means (general ends), one segment per lane of wave 0.
    if (tid < T) {
        const int e  = ends[b * T + tid];
        const int st = (tid == 0) ? 0 : (ends[b * T + tid - 1] + 1);
        float s = 0.0f;
        for (int i = st; i <= e; ++i) s += ds[PAD(i)];
        tt[tid] = s / (float)(e - st + 1);
    }
    __syncthreads();

    // Suffix LSE per j (62 lanes active).
    float sum = 0.0f;
    if (tid < J) {
        float M = -1e30f;
        for (int m = tid + 2; m < T; ++m) M = fmaxf(M, tt[m]);
        float a = 0.0f;
        for (int m = tid + 2; m < T; ++m) a += __expf(tt[m] - M);
        sum = logf(a) + M - tt[tid + 2];
    }

#pragma unroll
    for (int off = 32; off >= 1; off >>= 1)
        sum += __shfl_xor(sum, off, 64);
    if ((tid & 63) == 0) partial[tid >> 6] = sum;
    __syncthreads();
    if (tid == 0) loss_b[b] = partial[0] + partial[1] + partial[2] + partial[3];
}

// Kernel 3: final mean over B batches (one wave).
__global__ __launch_bounds__(64) void final_kernel(
    const float* __restrict__ loss_b,
    float* __restrict__ out) {
    const int lane = threadIdx.x;
    float v = (lane < B) ? loss_b[lane] : 0.0f;
#pragma unroll
    for (int off = 32; off >= 1; off >>= 1)
        v += __shfl_xor(v, off, 64);
    if (lane == 0) out[0] = v / (float)(B * J);
}

extern "C" void kernel_launch(void* const* d_in, const int* in_sizes, int n_in,
                              void* d_out, int out_size, void* d_ws, size_t ws_size,
                              hipStream_t stream) {
    // Inputs: 0 encoder_output (B,S,E) f32; 1 his_turn_end_ids (B,T) i32;
    // 2..5 LSTM weights (algebraically dead); 6 fc_w (1,H+E); 7 fc_b (dead).
    // loss[b,j] = LSE_{m=j+2..T-1}(t[b,m]) - t[b,j+2], t = seg_mean(enc) @ We,
    // We = fc_w[0, H:]. LSTM path and fc_b cancel inside LSE - logits[...,0].
    const float* enc  = (const float*)d_in[0];
    const int*   ends = (const int*)d_in[1];
    const float* We   = (const float*)d_in[6] + H;

    float* d      = (float*)d_ws;       // B*S floats = 512 KiB
    float* loss_b = d + (size_t)B * S;  // B floats
    float* out    = (float*)d_out;

    row_dot_kernel<<<(B * S) / 4, 256, 0, stream>>>(enc, We, d);
    batch_loss_kernel<<<B, 256, 0, stream>>>(d, ends, loss_b);
    final_kernel<<<1, 64, 0, stream>>>(loss_b, out);
}